// Round 5
// baseline (218.375 us; speedup 1.0000x reference)
//
#include <hip/hip_runtime.h>
#include <math.h>

// hybridDynamicSimNew: B=65536 cars, H=5, F=50. One thread/car, 1 wave/SIMD
// (structural floor) -> VGPR file is 512/wave, all latency hiding is ILP.
//
// R5 vs R4 (110us kernel, VGPR=244, VALUBusy 57%):
//  1. GEMV rewritten as per-component scalar fmaf -- R4's
//     __builtin_elementwise_fma(wr, splat16(f), y1) materialized the splat
//     (~400 v_mov/step). A scalar VGPR operand is shared by all 16 FMAs.
//  2. fc1 rows k=0..19 pinned in VGPRs via asm "+v" on float4-vectors
//     (asm outputs cannot be remat'd from LDS -> true residency; R4's
//     allocator sank the loads back into the loop at VGPR=244).
//     Rows k=20..24 stay in LDS: 10 uniform-broadcast ds_read_b128/step.
//  3. b1 / fc2 / params in SGPRs via readfirstlane, folded into FMAs as the
//     one allowed SGPR source operand (zero v_mov).
// Numerics byte-identical to the passing R4 (absmax 0.027).

typedef float f4v __attribute__((ext_vector_type(4)));

__device__ __forceinline__ float rfl(float x) {
    return __int_as_float(__builtin_amdgcn_readfirstlane(__float_as_int(x)));
}

__device__ __forceinline__ float fast_tanhf(float x) {
    float e = __builtin_amdgcn_exp2f(x * 2.8853900817779268f);
    return 1.0f - 2.0f * __builtin_amdgcn_rcpf(e + 1.0f);
}

// sin(x) for |x| <= ~0.16 (tire model: |tC*atan| <= 0.1*pi/2)
__device__ __forceinline__ float sin_small(float x) {
    float x2 = x * x;
    return x * (1.0f + x2 * (-1.66666667e-1f + x2 * 8.33333338e-3f));
}

// branchless full-range atan, max err ~1.5e-6 rad
__device__ __forceinline__ float fatanf(float x) {
    float ax = fabsf(x);
    bool big = ax > 1.0f;
    float z  = big ? __builtin_amdgcn_rcpf(ax) : ax;
    float z2 = z * z;
    float p = fmaf(z2, -0.0117212f, 0.05265332f);
    p = fmaf(z2, p, -0.11643287f);
    p = fmaf(z2, p,  0.19354346f);
    p = fmaf(z2, p, -0.33262347f);
    p = fmaf(z2, p,  0.99997726f);
    float r = z * p;
    r = big ? (1.57079632679489662f - r) : r;
    return copysignf(r, x);
}

// acc[i] += f * w[i], scalar fmaf per component (no splat materialization)
__device__ __forceinline__ f4v fma4(float f, f4v w, f4v acc) {
    acc[0] = fmaf(f, w[0], acc[0]);
    acc[1] = fmaf(f, w[1], acc[1]);
    acc[2] = fmaf(f, w[2], acc[2]);
    acc[3] = fmaf(f, w[3], acc[3]);
    return acc;
}

// acc[i] = f * w[i] + b_i  (b_i are SGPR floats: VOP3 1-SGPR-src rule ok)
__device__ __forceinline__ f4v fma4_init(float f, f4v w, float s0, float s1,
                                         float s2, float s3) {
    f4v acc;
    acc[0] = fmaf(f, w[0], s0);
    acc[1] = fmaf(f, w[1], s1);
    acc[2] = fmaf(f, w[2], s2);
    acc[3] = fmaf(f, w[3], s3);
    return acc;
}

__global__ __launch_bounds__(256, 1)
void sim_kernel(const float* __restrict__ fs,   // (B,5,8)
                const float* __restrict__ act,  // (B,50,2)
                const float* __restrict__ w1,   // (16,25) [o][k]
                const float* __restrict__ b1,   // (16)
                const float* __restrict__ w2,   // (3,16)
                const float* __restrict__ b2,   // (3)
                const float* __restrict__ prm,  // (10)
                const int*   __restrict__ rnnp, // (1)
                float* __restrict__ out)        // (B,50,8)
{
    __shared__ float sW1t[25 * 16];  // transposed: sW1t[k*16+o] = w1[o][k]

    const int tid = threadIdx.x;
    for (int i = tid; i < 400; i += 256) {
        int o = i & 15;
        int k = i >> 4;
        sW1t[i] = w1[o * 25 + k];
    }
    __syncthreads();

    const int b = blockIdx.x * 256 + tid;

    const float4* fsp = reinterpret_cast<const float4*>(fs + (size_t)b * 40);
    const float4* ap  = reinterpret_cast<const float4*>(act + (size_t)b * 100);
    float4 acur = ap[0];

    float wf[40];
#pragma unroll
    for (int i = 0; i < 10; ++i) {
        float4 v = fsp[i];
        wf[i * 4 + 0] = v.x; wf[i * 4 + 1] = v.y;
        wf[i * 4 + 2] = v.z; wf[i * 4 + 3] = v.w;
    }

    // wave-uniform params -> SGPR
    const float lf = rfl(prm[0]), lr = rfl(prm[1]), mIz = rfl(prm[2]);
    const float cm1 = rfl(prm[3]), cm2 = rfl(prm[4]), cr = rfl(prm[5]);
    const float cd = rfl(prm[6]);
    const float tB = rfl(prm[7]), tC = rfl(prm[8]), tD = rfl(prm[9]);
    const int   rnn = __builtin_amdgcn_readfirstlane(rnnp[0]);
    const float dt = 0.01f;
    const float PI = 3.14159265358979323846f;
    const float INV2PI = 0.15915494309189535f;
    const float TWOPI = 6.28318530717958647692f;

    // fc2 weights + b2 + b1 -> SGPRs
#define DECLW2(K) \
    float w2a_##K = rfl(w2[(K)]);      \
    float w2b_##K = rfl(w2[16 + (K)]); \
    float w2c_##K = rfl(w2[32 + (K)]);
    DECLW2(0) DECLW2(1) DECLW2(2) DECLW2(3)
    DECLW2(4) DECLW2(5) DECLW2(6) DECLW2(7)
    DECLW2(8) DECLW2(9) DECLW2(10) DECLW2(11)
    DECLW2(12) DECLW2(13) DECLW2(14) DECLW2(15)
#undef DECLW2
    const float b2s0 = rfl(b2[0]), b2s1 = rfl(b2[1]), b2s2 = rfl(b2[2]);
#define DECLB1(K) float b1s_##K = rfl(b1[(K)]);
    DECLB1(0) DECLB1(1) DECLB1(2) DECLB1(3)
    DECLB1(4) DECLB1(5) DECLB1(6) DECLB1(7)
    DECLB1(8) DECLB1(9) DECLB1(10) DECLB1(11)
    DECLB1(12) DECLB1(13) DECLB1(14) DECLB1(15)
#undef DECLB1

    // ---- initial feature window ----
    // feat: [Vxh(0..4), Vyh(5..9), omega(10..14), thr(15..19), steer(20..24)]
    float feat[25];
#pragma unroll
    for (int t = 0; t < 5; ++t) {
        float ph = wf[t * 8 + 4];
        float ch = __cosf(ph), sh = __sinf(ph);
        float v1 = wf[t * 8 + 1], v3 = wf[t * 8 + 3];
        feat[t]      =  v1 * ch + v3 * sh;
        feat[5 + t]  = -v1 * sh + v3 * ch;
        feat[10 + t] = wf[t * 8 + 5];
        feat[15 + t] = wf[t * 8 + 6];
        feat[20 + t] = wf[t * 8 + 7];
    }

    float x   = wf[32];
    float y   = wf[34];
    float psi = wf[36];
    float c = __cosf(psi), s = __sinf(psi);

    // ---- fc1 rows k=0..19: 80 named f4v quads, loaded then PINNED ----
#define DECLROW(K)                                                           \
    f4v wq##K##_0, wq##K##_1, wq##K##_2, wq##K##_3;                          \
    {                                                                        \
        const f4v* sp = reinterpret_cast<const f4v*>(&sW1t[(K) * 16]);       \
        wq##K##_0 = sp[0]; wq##K##_1 = sp[1];                                \
        wq##K##_2 = sp[2]; wq##K##_3 = sp[3];                                \
    }                                                                        \
    asm volatile("" : "+v"(wq##K##_0), "+v"(wq##K##_1), "+v"(wq##K##_2),     \
                      "+v"(wq##K##_3));
    DECLROW(0) DECLROW(1) DECLROW(2) DECLROW(3) DECLROW(4)
    DECLROW(5) DECLROW(6) DECLROW(7) DECLROW(8) DECLROW(9)
    DECLROW(10) DECLROW(11) DECLROW(12) DECLROW(13) DECLROW(14)
    DECLROW(15) DECLROW(16) DECLROW(17) DECLROW(18) DECLROW(19)
#undef DECLROW

    float* outp = out + (size_t)b * 400;

#pragma unroll 1
    for (int f2 = 0; f2 < 25; ++f2) {
        float4 anext = ap[(f2 < 24) ? (f2 + 1) : 24];

#pragma unroll
        for (int half = 0; half < 2; ++half) {
            const float a0 = half ? acur.z : acur.x;
            const float a1 = half ? acur.w : acur.y;

            // ---- physics ----
            const float throttle = feat[19];
            const float steering = feat[24];
            const float Vx = feat[4];
            const float Vy = feat[9];

            const float atr    = fatanf(Vy * __builtin_amdgcn_rcpf(Vx));
            const float slip_f = -atr + steering;
            const float slip_r = -atr;
            const float laf = tD * sin_small(tC * fatanf(tB * slip_f));
            const float lar = tD * sin_small(tC * fatanf(tB * slip_r));

            const float st_s = __sinf(steering), st_c = __cosf(steering);
            const float fwd  = (cm1 - cm2 * Vx) * throttle - cr - cd * Vx * Vx;

            float Vx2   = Vx + (fwd - laf * st_s) * dt;
            float Vy2   = Vy + (lar + laf * st_c) * dt;
            float omega = mIz * (laf * lf * st_c - lar * lr) * dt;

            // ---- RNN (wave-uniform branch) ----
            if (rnn) {
                // k=0 folds b1 (SGPR) into the first FMA
                f4v y1a = fma4_init(feat[0], wq0_0, b1s_0, b1s_1, b1s_2, b1s_3);
                f4v y1b = fma4_init(feat[0], wq0_1, b1s_4, b1s_5, b1s_6, b1s_7);
                f4v y1c = fma4_init(feat[0], wq0_2, b1s_8, b1s_9, b1s_10, b1s_11);
                f4v y1d = fma4_init(feat[0], wq0_3, b1s_12, b1s_13, b1s_14, b1s_15);
#define GK(K)                                          \
                y1a = fma4(feat[(K)], wq##K##_0, y1a); \
                y1b = fma4(feat[(K)], wq##K##_1, y1b); \
                y1c = fma4(feat[(K)], wq##K##_2, y1c); \
                y1d = fma4(feat[(K)], wq##K##_3, y1d);
                GK(1) GK(2) GK(3) GK(4)
                GK(5) GK(6) GK(7) GK(8) GK(9)
                GK(10) GK(11) GK(12) GK(13) GK(14)
                GK(15) GK(16) GK(17) GK(18) GK(19)
#undef GK
                // rows k=20..24 from LDS (uniform-address b128 broadcasts)
#define GKL(K)                                                               \
                {                                                            \
                    const f4v* sp =                                          \
                        reinterpret_cast<const f4v*>(&sW1t[(K) * 16]);       \
                    const float fk = feat[(K)];                              \
                    y1a = fma4(fk, sp[0], y1a);                              \
                    y1b = fma4(fk, sp[1], y1b);                              \
                    y1c = fma4(fk, sp[2], y1c);                              \
                    y1d = fma4(fk, sp[3], y1d);                              \
                }
                GKL(20) GKL(21) GKL(22) GKL(23) GKL(24)
#undef GKL

                float z0 = b2s0, z1 = b2s1, z2 = b2s2;
#define FC2(Q, I, K)                                   \
                {                                      \
                    float t_ = fast_tanhf(y1##Q[(I)]); \
                    z0 = fmaf(t_, w2a_##K, z0);        \
                    z1 = fmaf(t_, w2b_##K, z1);        \
                    z2 = fmaf(t_, w2c_##K, z2);        \
                }
                FC2(a, 0, 0) FC2(a, 1, 1) FC2(a, 2, 2) FC2(a, 3, 3)
                FC2(b, 0, 4) FC2(b, 1, 5) FC2(b, 2, 6) FC2(b, 3, 7)
                FC2(c, 0, 8) FC2(c, 1, 9) FC2(c, 2, 10) FC2(c, 3, 11)
                FC2(d, 0, 12) FC2(d, 1, 13) FC2(d, 2, 14) FC2(d, 3, 15)
#undef FC2
                Vx2   += fast_tanhf(z0) * 5.0f * dt;
                Vy2   += fast_tanhf(z1) * 5.0f * dt;
                omega += fast_tanhf(z2) * 3.0f * dt;
            }

            // ---- global-frame update ----
            const float Vxg = Vx2 * c - Vy2 * s;
            const float Vyg = Vx2 * s + Vy2 * c;
            float pn = psi + omega * dt + PI;
            pn = pn - floorf(pn * INV2PI) * TWOPI - PI;

            x = x + Vxg * dt;
            y = y + Vyg * dt;

            float4 o0 = make_float4(x, Vxg, y, Vyg);
            float4 o1 = make_float4(pn, omega, a0, a1);
            reinterpret_cast<float4*>(outp)[0] = o0;
            reinterpret_cast<float4*>(outp)[1] = o1;
            outp += 8;

            // ---- advance / shift window ----
            psi = pn;
            c = __cosf(pn);
            s = __sinf(pn);
#pragma unroll
            for (int j = 0; j < 5; ++j)
#pragma unroll
                for (int t = 0; t < 4; ++t)
                    feat[j * 5 + t] = feat[j * 5 + t + 1];
            feat[4]  =  Vxg * c + Vyg * s;
            feat[9]  = -Vxg * s + Vyg * c;
            feat[14] = omega;
            feat[19] = a0;
            feat[24] = a1;
        }
        acur = anext;
    }
}

extern "C" void kernel_launch(void* const* d_in, const int* in_sizes, int n_in,
                              void* d_out, int out_size, void* d_ws, size_t ws_size,
                              hipStream_t stream) {
    const float* fs  = (const float*)d_in[0];
    const float* act = (const float*)d_in[1];
    const float* w1  = (const float*)d_in[2];
    const float* b1  = (const float*)d_in[3];
    const float* w2  = (const float*)d_in[4];
    const float* b2  = (const float*)d_in[5];
    const float* prm = (const float*)d_in[6];
    const int*   rnn = (const int*)d_in[7];
    float* out = (float*)d_out;

    const int Bn = in_sizes[0] / 40;  // 65536
    dim3 grid(Bn / 256), block(256);
    hipLaunchKernelGGL(sim_kernel, grid, block, 0, stream,
                       fs, act, w1, b1, w2, b2, prm, rnn, out);
}

// Round 6
// 213.486 us; speedup vs baseline: 1.0229x; 1.0229x over previous
//
#include <hip/hip_runtime.h>
#include <hip/hip_fp16.h>
#include <math.h>

// hybridDynamicSimNew: B=65536 cars, H=5, F=50. One thread/car = 1024 waves
// = structurally 1 wave/SIMD.
//
// R6 root-cause fix: R4/R5 both allocated ~240 VGPRs (just under 256) -- the
// allocator targets a 2-waves/EU budget and SINKS the fc1 weight loads back
// into the loop (per-step LDS re-reads ~= 800+ cy/wave of LDS reg-write BW,
// the measured 3x gap vs the instruction model). Two levers:
//  1. amdgpu_waves_per_eu(1,1): occupancy target = 1 wave/EU (all we can use
//     anyway at 1024 waves) -> full 512-reg file, no sinking incentive.
//  2. fc1 weights as packed f16 pairs in 200 VGPRs, consumed by
//     v_fma_mix_f32 (f16 src0 via op_sel, f32 feat, f32 accumulate): same
//     400-inst GEMV, half the register footprint, no splat/cvt overhead.
//     Total live ~295 regs -> big slack. Only numeric change: weight
//     quantization to f16 (|dw| <= 2^-11 |w|), f32 math everywhere else.

__device__ __forceinline__ float rfl(float x) {
    return __int_as_float(__builtin_amdgcn_readfirstlane(__float_as_int(x)));
}

// d = f16(lo16(w)) * f + acc   (f32 multiply-accumulate of an f16 source)
__device__ __forceinline__ float mixlo(unsigned int w, float f, float acc) {
    float d;
    asm("v_fma_mix_f32 %0, %1, %2, %3 op_sel:[0,0,0] op_sel_hi:[1,0,0]"
        : "=v"(d) : "v"(w), "v"(f), "v"(acc));
    return d;
}
// d = f16(hi16(w)) * f + acc
__device__ __forceinline__ float mixhi(unsigned int w, float f, float acc) {
    float d;
    asm("v_fma_mix_f32 %0, %1, %2, %3 op_sel:[1,0,0] op_sel_hi:[1,0,0]"
        : "=v"(d) : "v"(w), "v"(f), "v"(acc));
    return d;
}

__device__ __forceinline__ float fast_tanhf(float x) {
    float e = __builtin_amdgcn_exp2f(x * 2.8853900817779268f);
    return 1.0f - 2.0f * __builtin_amdgcn_rcpf(e + 1.0f);
}

// sin(x) for |x| <= ~0.16 (tire model: |tC*atan| <= 0.1*pi/2)
__device__ __forceinline__ float sin_small(float x) {
    float x2 = x * x;
    return x * (1.0f + x2 * (-1.66666667e-1f + x2 * 8.33333338e-3f));
}

// branchless full-range atan, max err ~1.5e-6 rad
__device__ __forceinline__ float fatanf(float x) {
    float ax = fabsf(x);
    bool big = ax > 1.0f;
    float z  = big ? __builtin_amdgcn_rcpf(ax) : ax;
    float z2 = z * z;
    float p = fmaf(z2, -0.0117212f, 0.05265332f);
    p = fmaf(z2, p, -0.11643287f);
    p = fmaf(z2, p,  0.19354346f);
    p = fmaf(z2, p, -0.33262347f);
    p = fmaf(z2, p,  0.99997726f);
    float r = z * p;
    r = big ? (1.57079632679489662f - r) : r;
    return copysignf(r, x);
}

// X-macro over k = 0..24 (k=0 handled separately to fold in b1)
#define FOR_K_TAIL(M) \
    M(1) M(2) M(3) M(4) M(5) M(6) M(7) M(8) M(9) M(10) M(11) M(12) \
    M(13) M(14) M(15) M(16) M(17) M(18) M(19) M(20) M(21) M(22) M(23) M(24)
#define FOR_K_ALL(M) M(0) FOR_K_TAIL(M)

__global__ __launch_bounds__(256)
__attribute__((amdgpu_waves_per_eu(1, 1)))
void sim_kernel(const float* __restrict__ fs,   // (B,5,8)
                const float* __restrict__ act,  // (B,50,2)
                const float* __restrict__ w1,   // (16,25) [o][k]
                const float* __restrict__ b1,   // (16)
                const float* __restrict__ w2,   // (3,16)
                const float* __restrict__ b2,   // (3)
                const float* __restrict__ prm,  // (10)
                const int*   __restrict__ rnnp, // (1)
                float* __restrict__ out)        // (B,50,8)
{
    // packed f16 weight pairs: sWH[k*8+j] = (f16 w1[2j+1][k])<<16 | f16 w1[2j][k]
    __shared__ unsigned int sWH[200];

    const int tid = threadIdx.x;
    if (tid < 200) {
        int k = tid >> 3, j = tid & 7;
        unsigned int lo = (unsigned int)__half_as_ushort(__float2half(w1[(2 * j) * 25 + k]));
        unsigned int hi = (unsigned int)__half_as_ushort(__float2half(w1[(2 * j + 1) * 25 + k]));
        sWH[tid] = lo | (hi << 16);
    }
    __syncthreads();

    const int b = blockIdx.x * 256 + tid;

    const float4* fsp = reinterpret_cast<const float4*>(fs + (size_t)b * 40);
    const float4* ap  = reinterpret_cast<const float4*>(act + (size_t)b * 100);
    float4 acur = ap[0];

    float wf[40];
#pragma unroll
    for (int i = 0; i < 10; ++i) {
        float4 v = fsp[i];
        wf[i * 4 + 0] = v.x; wf[i * 4 + 1] = v.y;
        wf[i * 4 + 2] = v.z; wf[i * 4 + 3] = v.w;
    }

    // wave-uniform params -> SGPR
    const float lf = rfl(prm[0]), lr = rfl(prm[1]), mIz = rfl(prm[2]);
    const float cm1 = rfl(prm[3]), cm2 = rfl(prm[4]), cr = rfl(prm[5]);
    const float cd = rfl(prm[6]);
    const float tB = rfl(prm[7]), tC = rfl(prm[8]), tD = rfl(prm[9]);
    const int   rnn = __builtin_amdgcn_readfirstlane(rnnp[0]);
    const float dt = 0.01f;
    const float PI = 3.14159265358979323846f;
    const float INV2PI = 0.15915494309189535f;
    const float TWOPI = 6.28318530717958647692f;

    // fc2 weights + b2 -> SGPR (folded into scalar fmaf as the 1 SGPR src)
#define DECLW2(K) \
    float w2a_##K = rfl(w2[(K)]);      \
    float w2b_##K = rfl(w2[16 + (K)]); \
    float w2c_##K = rfl(w2[32 + (K)]);
    DECLW2(0) DECLW2(1) DECLW2(2) DECLW2(3)
    DECLW2(4) DECLW2(5) DECLW2(6) DECLW2(7)
    DECLW2(8) DECLW2(9) DECLW2(10) DECLW2(11)
    DECLW2(12) DECLW2(13) DECLW2(14) DECLW2(15)
#undef DECLW2
    const float b2s0 = rfl(b2[0]), b2s1 = rfl(b2[1]), b2s2 = rfl(b2[2]);

    // b1 in VGPRs (y1 init values for the k=0 fma_mix)
#define DECLB1(K) float b1v_##K = b1[(K)];
    DECLB1(0) DECLB1(1) DECLB1(2) DECLB1(3)
    DECLB1(4) DECLB1(5) DECLB1(6) DECLB1(7)
    DECLB1(8) DECLB1(9) DECLB1(10) DECLB1(11)
    DECLB1(12) DECLB1(13) DECLB1(14) DECLB1(15)
#undef DECLB1

    // ---- initial feature window ----
    // feat: [Vxh(0..4), Vyh(5..9), omega(10..14), thr(15..19), steer(20..24)]
    float feat[25];
#pragma unroll
    for (int t = 0; t < 5; ++t) {
        float ph = wf[t * 8 + 4];
        float ch = __cosf(ph), sh = __sinf(ph);
        float v1 = wf[t * 8 + 1], v3 = wf[t * 8 + 3];
        feat[t]      =  v1 * ch + v3 * sh;
        feat[5 + t]  = -v1 * sh + v3 * ch;
        feat[10 + t] = wf[t * 8 + 5];
        feat[15 + t] = wf[t * 8 + 6];
        feat[20 + t] = wf[t * 8 + 7];
    }

    float x   = wf[32];
    float y   = wf[34];
    float psi = wf[36];
    float c = __cosf(psi), s = __sinf(psi);

    // ---- fc1 weights: 200 named packed-f16 uints (full residency) ----
#define WLOAD(K)                                                             \
    unsigned int wp##K##_0, wp##K##_1, wp##K##_2, wp##K##_3,                 \
                 wp##K##_4, wp##K##_5, wp##K##_6, wp##K##_7;                 \
    {                                                                        \
        const uint4* p = reinterpret_cast<const uint4*>(&sWH[(K) * 8]);      \
        uint4 u0 = p[0], u1 = p[1];                                          \
        wp##K##_0 = u0.x; wp##K##_1 = u0.y;                                  \
        wp##K##_2 = u0.z; wp##K##_3 = u0.w;                                  \
        wp##K##_4 = u1.x; wp##K##_5 = u1.y;                                  \
        wp##K##_6 = u1.z; wp##K##_7 = u1.w;                                  \
    }
    FOR_K_ALL(WLOAD)
#undef WLOAD

    float* outp = out + (size_t)b * 400;

#pragma unroll 1
    for (int f2 = 0; f2 < 25; ++f2) {
        float4 anext = ap[(f2 < 24) ? (f2 + 1) : 24];

#pragma unroll
        for (int half = 0; half < 2; ++half) {
            const float a0 = half ? acur.z : acur.x;
            const float a1 = half ? acur.w : acur.y;

            // ---- physics ----
            const float throttle = feat[19];
            const float steering = feat[24];
            const float Vx = feat[4];
            const float Vy = feat[9];

            const float atr    = fatanf(Vy * __builtin_amdgcn_rcpf(Vx));
            const float slip_f = -atr + steering;
            const float slip_r = -atr;
            const float laf = tD * sin_small(tC * fatanf(tB * slip_f));
            const float lar = tD * sin_small(tC * fatanf(tB * slip_r));

            const float st_s = __sinf(steering), st_c = __cosf(steering);
            const float fwd  = (cm1 - cm2 * Vx) * throttle - cr - cd * Vx * Vx;

            float Vx2   = Vx + (fwd - laf * st_s) * dt;
            float Vy2   = Vy + (lar + laf * st_c) * dt;
            float omega = mIz * (laf * lf * st_c - lar * lr) * dt;

            // ---- RNN (wave-uniform branch) ----
            if (rnn) {
                // k=0: y1_o = w[o][0]*feat[0] + b1[o]
                const float f0 = feat[0];
                float y1_0  = mixlo(wp0_0, f0, b1v_0);
                float y1_1  = mixhi(wp0_0, f0, b1v_1);
                float y1_2  = mixlo(wp0_1, f0, b1v_2);
                float y1_3  = mixhi(wp0_1, f0, b1v_3);
                float y1_4  = mixlo(wp0_2, f0, b1v_4);
                float y1_5  = mixhi(wp0_2, f0, b1v_5);
                float y1_6  = mixlo(wp0_3, f0, b1v_6);
                float y1_7  = mixhi(wp0_3, f0, b1v_7);
                float y1_8  = mixlo(wp0_4, f0, b1v_8);
                float y1_9  = mixhi(wp0_4, f0, b1v_9);
                float y1_10 = mixlo(wp0_5, f0, b1v_10);
                float y1_11 = mixhi(wp0_5, f0, b1v_11);
                float y1_12 = mixlo(wp0_6, f0, b1v_12);
                float y1_13 = mixhi(wp0_6, f0, b1v_13);
                float y1_14 = mixlo(wp0_7, f0, b1v_14);
                float y1_15 = mixhi(wp0_7, f0, b1v_15);
#define GK(K)                                        \
                {                                    \
                    const float fk = feat[(K)];      \
                    y1_0  = mixlo(wp##K##_0, fk, y1_0);  \
                    y1_1  = mixhi(wp##K##_0, fk, y1_1);  \
                    y1_2  = mixlo(wp##K##_1, fk, y1_2);  \
                    y1_3  = mixhi(wp##K##_1, fk, y1_3);  \
                    y1_4  = mixlo(wp##K##_2, fk, y1_4);  \
                    y1_5  = mixhi(wp##K##_2, fk, y1_5);  \
                    y1_6  = mixlo(wp##K##_3, fk, y1_6);  \
                    y1_7  = mixhi(wp##K##_3, fk, y1_7);  \
                    y1_8  = mixlo(wp##K##_4, fk, y1_8);  \
                    y1_9  = mixhi(wp##K##_4, fk, y1_9);  \
                    y1_10 = mixlo(wp##K##_5, fk, y1_10); \
                    y1_11 = mixhi(wp##K##_5, fk, y1_11); \
                    y1_12 = mixlo(wp##K##_6, fk, y1_12); \
                    y1_13 = mixhi(wp##K##_6, fk, y1_13); \
                    y1_14 = mixlo(wp##K##_7, fk, y1_14); \
                    y1_15 = mixhi(wp##K##_7, fk, y1_15); \
                }
                FOR_K_TAIL(GK)
#undef GK

                float z0 = b2s0, z1 = b2s1, z2 = b2s2;
#define FC2(K)                                       \
                {                                    \
                    float t_ = fast_tanhf(y1_##K);   \
                    z0 = fmaf(t_, w2a_##K, z0);      \
                    z1 = fmaf(t_, w2b_##K, z1);      \
                    z2 = fmaf(t_, w2c_##K, z2);      \
                }
                FC2(0) FC2(1) FC2(2) FC2(3)
                FC2(4) FC2(5) FC2(6) FC2(7)
                FC2(8) FC2(9) FC2(10) FC2(11)
                FC2(12) FC2(13) FC2(14) FC2(15)
#undef FC2
                Vx2   += fast_tanhf(z0) * 5.0f * dt;
                Vy2   += fast_tanhf(z1) * 5.0f * dt;
                omega += fast_tanhf(z2) * 3.0f * dt;
            }

            // ---- global-frame update ----
            const float Vxg = Vx2 * c - Vy2 * s;
            const float Vyg = Vx2 * s + Vy2 * c;
            float pn = psi + omega * dt + PI;
            pn = pn - floorf(pn * INV2PI) * TWOPI - PI;

            x = x + Vxg * dt;
            y = y + Vyg * dt;

            float4 o0 = make_float4(x, Vxg, y, Vyg);
            float4 o1 = make_float4(pn, omega, a0, a1);
            reinterpret_cast<float4*>(outp)[0] = o0;
            reinterpret_cast<float4*>(outp)[1] = o1;
            outp += 8;

            // ---- advance / shift window ----
            psi = pn;
            c = __cosf(pn);
            s = __sinf(pn);
#pragma unroll
            for (int j = 0; j < 5; ++j)
#pragma unroll
                for (int t = 0; t < 4; ++t)
                    feat[j * 5 + t] = feat[j * 5 + t + 1];
            feat[4]  =  Vxg * c + Vyg * s;
            feat[9]  = -Vxg * s + Vyg * c;
            feat[14] = omega;
            feat[19] = a0;
            feat[24] = a1;
        }
        acur = anext;
    }
}

extern "C" void kernel_launch(void* const* d_in, const int* in_sizes, int n_in,
                              void* d_out, int out_size, void* d_ws, size_t ws_size,
                              hipStream_t stream) {
    const float* fs  = (const float*)d_in[0];
    const float* act = (const float*)d_in[1];
    const float* w1  = (const float*)d_in[2];
    const float* b1  = (const float*)d_in[3];
    const float* w2  = (const float*)d_in[4];
    const float* b2  = (const float*)d_in[5];
    const float* prm = (const float*)d_in[6];
    const int*   rnn = (const int*)d_in[7];
    float* out = (float*)d_out;

    const int Bn = in_sizes[0] / 40;  // 65536
    dim3 grid(Bn / 256), block(256);
    hipLaunchKernelGGL(sim_kernel, grid, block, 0, stream,
                       fs, act, w1, b1, w2, b2, prm, rnn, out);
}

// Round 7
// 206.840 us; speedup vs baseline: 1.0558x; 1.0321x over previous
//
#include <hip/hip_runtime.h>
#include <hip/hip_fp16.h>
#include <math.h>

// hybridDynamicSimNew: B=65536 cars, H=5, F=50.
//
// R7: TWO THREADS PER CAR (h = tid&1 owns y1 outputs 8h..8h+7).
// Rationale: R4/R5/R6 all failed to keep fc1 weights VGPR-resident
// (VGPR_Count 244/236/136 -- the scheduler sinks weight loads into the loop
// to minimize pressure, and at 1 wave/SIMD nothing hides the resulting LDS
// latency). Splitting the car halves the weight footprint to 100 packed-f16
// uints/thread -> total live ~200 regs, inside the 256-reg budget at
// 2 waves/EU (amdgpu_waves_per_eu(2,2) pins the allocator target), AND the
// doubled grid gives 2 waves/SIMD of real latency hiding.
// GEMV asm is now TIED ("+v" acc as both dst and C-src -> in-place, no
// copies). fc2: per-thread partials over its 8 outputs + 3 shfl_xor(1)
// (quad-perm DPP). Physics duplicated in both threads (cheap, no divergence).
// Stores: h=0 writes {x,Vxg,y,Vyg}, h=1 writes {pn,omega,a0,a1}.
// Numerics identical to R6 (absmax 0.0557 passed) modulo fc2 partial-sum
// grouping.

__device__ __forceinline__ float rfl(float x) {
    return __int_as_float(__builtin_amdgcn_readfirstlane(__float_as_int(x)));
}

// acc = f16(lo16(w)) * f + acc   (tied: in-place accumulate, no mov)
__device__ __forceinline__ void mixlo_acc(float& acc, unsigned int w, float f) {
    asm("v_fma_mix_f32 %0, %1, %2, %0 op_sel:[0,0,0] op_sel_hi:[1,0,0]"
        : "+v"(acc) : "v"(w), "v"(f));
}
__device__ __forceinline__ void mixhi_acc(float& acc, unsigned int w, float f) {
    asm("v_fma_mix_f32 %0, %1, %2, %0 op_sel:[1,0,0] op_sel_hi:[1,0,0]"
        : "+v"(acc) : "v"(w), "v"(f));
}
// d = f16(lo/hi16(w)) * f + c    (init form, c = b1 stays live)
__device__ __forceinline__ float mixlo_init(unsigned int w, float f, float c) {
    float d;
    asm("v_fma_mix_f32 %0, %1, %2, %3 op_sel:[0,0,0] op_sel_hi:[1,0,0]"
        : "=v"(d) : "v"(w), "v"(f), "v"(c));
    return d;
}
__device__ __forceinline__ float mixhi_init(unsigned int w, float f, float c) {
    float d;
    asm("v_fma_mix_f32 %0, %1, %2, %3 op_sel:[1,0,0] op_sel_hi:[1,0,0]"
        : "=v"(d) : "v"(w), "v"(f), "v"(c));
    return d;
}

__device__ __forceinline__ float fast_tanhf(float x) {
    float e = __builtin_amdgcn_exp2f(x * 2.8853900817779268f);
    return 1.0f - 2.0f * __builtin_amdgcn_rcpf(e + 1.0f);
}

// sin(x) for |x| <= ~0.16 (tire model: |tC*atan| <= 0.1*pi/2)
__device__ __forceinline__ float sin_small(float x) {
    float x2 = x * x;
    return x * (1.0f + x2 * (-1.66666667e-1f + x2 * 8.33333338e-3f));
}

// branchless full-range atan, max err ~1.5e-6 rad
__device__ __forceinline__ float fatanf(float x) {
    float ax = fabsf(x);
    bool big = ax > 1.0f;
    float z  = big ? __builtin_amdgcn_rcpf(ax) : ax;
    float z2 = z * z;
    float p = fmaf(z2, -0.0117212f, 0.05265332f);
    p = fmaf(z2, p, -0.11643287f);
    p = fmaf(z2, p,  0.19354346f);
    p = fmaf(z2, p, -0.33262347f);
    p = fmaf(z2, p,  0.99997726f);
    float r = z * p;
    r = big ? (1.57079632679489662f - r) : r;
    return copysignf(r, x);
}

#define FOR_K_TAIL(M) \
    M(1) M(2) M(3) M(4) M(5) M(6) M(7) M(8) M(9) M(10) M(11) M(12) \
    M(13) M(14) M(15) M(16) M(17) M(18) M(19) M(20) M(21) M(22) M(23) M(24)
#define FOR_K_ALL(M) M(0) FOR_K_TAIL(M)

__global__ __launch_bounds__(256)
__attribute__((amdgpu_waves_per_eu(2, 2)))
void sim_kernel(const float* __restrict__ fs,   // (B,5,8)
                const float* __restrict__ act,  // (B,50,2)
                const float* __restrict__ w1,   // (16,25) [o][k]
                const float* __restrict__ b1,   // (16)
                const float* __restrict__ w2,   // (3,16)
                const float* __restrict__ b2,   // (3)
                const float* __restrict__ prm,  // (10)
                const int*   __restrict__ rnnp, // (1)
                float* __restrict__ out)        // (B,50,8)
{
    // packed f16 pairs: sWH[k*8+j] = (f16 w1[2j+1][k])<<16 | f16 w1[2j][k]
    __shared__ unsigned int sWH[200];

    const int tid = threadIdx.x;
    if (tid < 200) {
        int k = tid >> 3, j = tid & 7;
        unsigned int lo = (unsigned int)__half_as_ushort(__float2half(w1[(2 * j) * 25 + k]));
        unsigned int hi = (unsigned int)__half_as_ushort(__float2half(w1[(2 * j + 1) * 25 + k]));
        sWH[tid] = lo | (hi << 16);
    }
    __syncthreads();

    const int gt  = blockIdx.x * 256 + tid;
    const int car = gt >> 1;
    const int h   = gt & 1;   // output half: o in [8h, 8h+8)

    const float4* fsp = reinterpret_cast<const float4*>(fs + (size_t)car * 40);
    const float4* ap  = reinterpret_cast<const float4*>(act + (size_t)car * 100);
    float4 acur = ap[0];

    float wf[40];
#pragma unroll
    for (int i = 0; i < 10; ++i) {
        float4 v = fsp[i];
        wf[i * 4 + 0] = v.x; wf[i * 4 + 1] = v.y;
        wf[i * 4 + 2] = v.z; wf[i * 4 + 3] = v.w;
    }

    // wave-uniform params -> SGPR
    const float lf = rfl(prm[0]), lr = rfl(prm[1]), mIz = rfl(prm[2]);
    const float cm1 = rfl(prm[3]), cm2 = rfl(prm[4]), cr = rfl(prm[5]);
    const float cd = rfl(prm[6]);
    const float tB = rfl(prm[7]), tC = rfl(prm[8]), tD = rfl(prm[9]);
    const int   rnn = __builtin_amdgcn_readfirstlane(rnnp[0]);
    const float dt = 0.01f;
    const float PI = 3.14159265358979323846f;
    const float INV2PI = 0.15915494309189535f;
    const float TWOPI = 6.28318530717958647692f;
    const float b2s0 = rfl(b2[0]), b2s1 = rfl(b2[1]), b2s2 = rfl(b2[2]);

    // per-lane h-dependent slices of b1 and fc2 (VGPRs, 8+24 regs)
    float b1v_0, b1v_1, b1v_2, b1v_3, b1v_4, b1v_5, b1v_6, b1v_7;
    {
        const float4* p = reinterpret_cast<const float4*>(b1 + 8 * h);
        float4 u0 = p[0], u1 = p[1];
        b1v_0 = u0.x; b1v_1 = u0.y; b1v_2 = u0.z; b1v_3 = u0.w;
        b1v_4 = u1.x; b1v_5 = u1.y; b1v_6 = u1.z; b1v_7 = u1.w;
    }
    float w2av_0, w2av_1, w2av_2, w2av_3, w2av_4, w2av_5, w2av_6, w2av_7;
    float w2bv_0, w2bv_1, w2bv_2, w2bv_3, w2bv_4, w2bv_5, w2bv_6, w2bv_7;
    float w2cv_0, w2cv_1, w2cv_2, w2cv_3, w2cv_4, w2cv_5, w2cv_6, w2cv_7;
    {
        const float4* pa = reinterpret_cast<const float4*>(w2 + 8 * h);
        float4 a0_ = pa[0], a1_ = pa[1];
        w2av_0 = a0_.x; w2av_1 = a0_.y; w2av_2 = a0_.z; w2av_3 = a0_.w;
        w2av_4 = a1_.x; w2av_5 = a1_.y; w2av_6 = a1_.z; w2av_7 = a1_.w;
        const float4* pb = reinterpret_cast<const float4*>(w2 + 16 + 8 * h);
        float4 b0_ = pb[0], b1_ = pb[1];
        w2bv_0 = b0_.x; w2bv_1 = b0_.y; w2bv_2 = b0_.z; w2bv_3 = b0_.w;
        w2bv_4 = b1_.x; w2bv_5 = b1_.y; w2bv_6 = b1_.z; w2bv_7 = b1_.w;
        const float4* pc = reinterpret_cast<const float4*>(w2 + 32 + 8 * h);
        float4 c0_ = pc[0], c1_ = pc[1];
        w2cv_0 = c0_.x; w2cv_1 = c0_.y; w2cv_2 = c0_.z; w2cv_3 = c0_.w;
        w2cv_4 = c1_.x; w2cv_5 = c1_.y; w2cv_6 = c1_.z; w2cv_7 = c1_.w;
    }

    // ---- initial feature window ----
    // feat: [Vxh(0..4), Vyh(5..9), omega(10..14), thr(15..19), steer(20..24)]
    float feat[25];
#pragma unroll
    for (int t = 0; t < 5; ++t) {
        float ph = wf[t * 8 + 4];
        float ch = __cosf(ph), sh = __sinf(ph);
        float v1 = wf[t * 8 + 1], v3 = wf[t * 8 + 3];
        feat[t]      =  v1 * ch + v3 * sh;
        feat[5 + t]  = -v1 * sh + v3 * ch;
        feat[10 + t] = wf[t * 8 + 5];
        feat[15 + t] = wf[t * 8 + 6];
        feat[20 + t] = wf[t * 8 + 7];
    }

    float x   = wf[32];
    float y   = wf[34];
    float psi = wf[36];
    float c = __cosf(psi), s = __sinf(psi);

    // ---- this thread's fc1 weight slice: 100 packed uints (j = 4h..4h+3) ----
#define WLOAD(K)                                                             \
    unsigned int wp##K##_0, wp##K##_1, wp##K##_2, wp##K##_3;                 \
    {                                                                        \
        const uint4* p =                                                     \
            reinterpret_cast<const uint4*>(&sWH[(K) * 8 + 4 * h]);           \
        uint4 u = *p;                                                        \
        wp##K##_0 = u.x; wp##K##_1 = u.y; wp##K##_2 = u.z; wp##K##_3 = u.w;  \
    }
    FOR_K_ALL(WLOAD)
#undef WLOAD

    float* outp = out + (size_t)car * 400 + 4 * h;

#pragma unroll 1
    for (int f2 = 0; f2 < 25; ++f2) {
        float4 anext = ap[(f2 < 24) ? (f2 + 1) : 24];

#pragma unroll
        for (int half = 0; half < 2; ++half) {
            const float a0 = half ? acur.z : acur.x;
            const float a1 = half ? acur.w : acur.y;

            // ---- physics (duplicated in both pair threads) ----
            const float throttle = feat[19];
            const float steering = feat[24];
            const float Vx = feat[4];
            const float Vy = feat[9];

            const float atr    = fatanf(Vy * __builtin_amdgcn_rcpf(Vx));
            const float slip_f = -atr + steering;
            const float slip_r = -atr;
            const float laf = tD * sin_small(tC * fatanf(tB * slip_f));
            const float lar = tD * sin_small(tC * fatanf(tB * slip_r));

            const float st_s = __sinf(steering), st_c = __cosf(steering);
            const float fwd  = (cm1 - cm2 * Vx) * throttle - cr - cd * Vx * Vx;

            float Vx2   = Vx + (fwd - laf * st_s) * dt;
            float Vy2   = Vy + (lar + laf * st_c) * dt;
            float omega = mIz * (laf * lf * st_c - lar * lr) * dt;

            // ---- RNN: this thread computes y1[8h..8h+7] ----
            if (rnn) {
                const float f0 = feat[0];
                float y1_0 = mixlo_init(wp0_0, f0, b1v_0);
                float y1_1 = mixhi_init(wp0_0, f0, b1v_1);
                float y1_2 = mixlo_init(wp0_1, f0, b1v_2);
                float y1_3 = mixhi_init(wp0_1, f0, b1v_3);
                float y1_4 = mixlo_init(wp0_2, f0, b1v_4);
                float y1_5 = mixhi_init(wp0_2, f0, b1v_5);
                float y1_6 = mixlo_init(wp0_3, f0, b1v_6);
                float y1_7 = mixhi_init(wp0_3, f0, b1v_7);
#define GK(K)                                                \
                {                                            \
                    const float fk = feat[(K)];              \
                    mixlo_acc(y1_0, wp##K##_0, fk);          \
                    mixhi_acc(y1_1, wp##K##_0, fk);          \
                    mixlo_acc(y1_2, wp##K##_1, fk);          \
                    mixhi_acc(y1_3, wp##K##_1, fk);          \
                    mixlo_acc(y1_4, wp##K##_2, fk);          \
                    mixhi_acc(y1_5, wp##K##_2, fk);          \
                    mixlo_acc(y1_6, wp##K##_3, fk);          \
                    mixhi_acc(y1_7, wp##K##_3, fk);          \
                }
                FOR_K_TAIL(GK)
#undef GK

                // fc2 partials over this thread's 8 outputs
                float p0 = 0.0f, p1 = 0.0f, p2 = 0.0f;
#define FC2(I)                                         \
                {                                      \
                    float t_ = fast_tanhf(y1_##I);     \
                    p0 = fmaf(t_, w2av_##I, p0);       \
                    p1 = fmaf(t_, w2bv_##I, p1);       \
                    p2 = fmaf(t_, w2cv_##I, p2);       \
                }
                FC2(0) FC2(1) FC2(2) FC2(3)
                FC2(4) FC2(5) FC2(6) FC2(7)
#undef FC2
                // combine with pair thread (lane^1): quad-perm DPP shuffle
                p0 += __shfl_xor(p0, 1, 64);
                p1 += __shfl_xor(p1, 1, 64);
                p2 += __shfl_xor(p2, 1, 64);

                Vx2   += fast_tanhf(b2s0 + p0) * 5.0f * dt;
                Vy2   += fast_tanhf(b2s1 + p1) * 5.0f * dt;
                omega += fast_tanhf(b2s2 + p2) * 3.0f * dt;
            }

            // ---- global-frame update (duplicated) ----
            const float Vxg = Vx2 * c - Vy2 * s;
            const float Vyg = Vx2 * s + Vy2 * c;
            float pn = psi + omega * dt + PI;
            pn = pn - floorf(pn * INV2PI) * TWOPI - PI;

            x = x + Vxg * dt;
            y = y + Vyg * dt;

            // ---- store: h=0 -> {x,Vxg,y,Vyg}, h=1 -> {pn,omega,a0,a1} ----
            float4 ov;
            ov.x = h ? pn    : x;
            ov.y = h ? omega : Vxg;
            ov.z = h ? a0    : y;
            ov.w = h ? a1    : Vyg;
            *reinterpret_cast<float4*>(outp) = ov;
            outp += 8;

            // ---- advance / shift window ----
            psi = pn;
            c = __cosf(pn);
            s = __sinf(pn);
#pragma unroll
            for (int j = 0; j < 5; ++j)
#pragma unroll
                for (int t = 0; t < 4; ++t)
                    feat[j * 5 + t] = feat[j * 5 + t + 1];
            feat[4]  =  Vxg * c + Vyg * s;
            feat[9]  = -Vxg * s + Vyg * c;
            feat[14] = omega;
            feat[19] = a0;
            feat[24] = a1;
        }
        acur = anext;
    }
}

extern "C" void kernel_launch(void* const* d_in, const int* in_sizes, int n_in,
                              void* d_out, int out_size, void* d_ws, size_t ws_size,
                              hipStream_t stream) {
    const float* fs  = (const float*)d_in[0];
    const float* act = (const float*)d_in[1];
    const float* w1  = (const float*)d_in[2];
    const float* b1  = (const float*)d_in[3];
    const float* w2  = (const float*)d_in[4];
    const float* b2  = (const float*)d_in[5];
    const float* prm = (const float*)d_in[6];
    const int*   rnn = (const int*)d_in[7];
    float* out = (float*)d_out;

    const int Bn = in_sizes[0] / 40;  // 65536 cars
    dim3 grid(Bn / 128), block(256);  // 2 threads per car
    hipLaunchKernelGGL(sim_kernel, grid, block, 0, stream,
                       fs, act, w1, b1, w2, b2, prm, rnn, out);
}

// Round 8
// 204.275 us; speedup vs baseline: 1.0690x; 1.0126x over previous
//
#include <hip/hip_runtime.h>
#include <hip/hip_fp16.h>
#include <math.h>

// hybridDynamicSimNew: B=65536 cars, H=5, F=50. R8: MFMA rewrite.
//
// R4-R7 all failed to keep the fc1 GEMV weights VGPR-resident (VGPR_Count
// 244/236/136/104 -- the allocator sinks weight loads into the loop; at
// 1-2 waves/SIMD the per-step LDS re-reads + waits are ~3x the instruction
// model). Fix: the per-step GEMV across cars IS a GEMM -> matrix pipe.
//   - 1 thread = 1 car; wave = 64 cars.
//   - fc1: y1(16xN) = W1(16x25)@F(25xN): 4 car-tiles x 2 k-halves x
//     {W_hi,W_lo} = 16x v_mfma_f32_16x16x16_f16, C-operand = b1.
//     W1 split hi+lo f16 => weight quantization error ~2^-21 (features f16
//     is the only new rounding, ~= R6's passing weight-f16 error).
//   - fc2: z(3xN) = W2@tanh(y1): tanh'd D-fragment of fc1 IS the B-fragment
//     of fc2 (same lane mapping) -> 8 MFMAs, C-operand = b2. z broadcast
//     back lane(l&15)->l via 12 shfl + 9 cndmask.
//   - Feature window: 15 packed-f16 uints/lane (5 cats x 6 k-slots, t=5
//     pad=0); shift = 2 v_alignbit + 1 cvt per cat. Staged per step to a
//     per-wave LDS region (128B rows, XOR swizzle (row&7)<<4, no barriers:
//     same-wave in-order DS), read back as B-frags (8x ds_read_b64).
//   - Weights now live in 24 VGPRs total -- nothing to sink.
// Fragment layouts (v_mfma_f32_16x16x16_f16, AMD matrix calculator +
// guide m89 D-verification): A[m][k]: m=l&15, k=4*(l>>4)+j. B[k][n]:
// n=l&15, k=4*(l>>4)+j. D[m][n]: n=l&15, m=4*(l>>4)+r.

typedef _Float16 h4_t __attribute__((ext_vector_type(4)));
typedef float f32x4 __attribute__((ext_vector_type(4)));

__device__ __forceinline__ float rfl(float x) {
    return __int_as_float(__builtin_amdgcn_readfirstlane(__float_as_int(x)));
}
__device__ __forceinline__ unsigned int cvt16(float v) {  // f32->f16 RTN, zext
    return (unsigned int)__half_as_ushort(__float2half(v));
}
__device__ __forceinline__ unsigned int pk_f16(float a, float b) {
    return cvt16(a) | (cvt16(b) << 16);
}
__device__ __forceinline__ h4_t mk_h4(unsigned int a, unsigned int b) {
    union { unsigned int u[2]; h4_t h; } v;
    v.u[0] = a; v.u[1] = b; return v.h;
}
__device__ __forceinline__ f32x4 mfma16(h4_t a, h4_t b, f32x4 c) {
    return __builtin_amdgcn_mfma_f32_16x16x16f16(a, b, c, 0, 0, 0);
}
__device__ __forceinline__ void split16(float v, unsigned int& hi,
                                        unsigned int& lo) {
    unsigned int h = cvt16(v);
    float hf = __half2float(__ushort_as_half((unsigned short)h));
    lo = cvt16(v - hf);
    hi = h;
}

__device__ __forceinline__ float fast_tanhf(float x) {
    float e = __builtin_amdgcn_exp2f(x * 2.8853900817779268f);
    return 1.0f - 2.0f * __builtin_amdgcn_rcpf(e + 1.0f);
}
// sin(x) for |x| <= ~0.16 (tire model: |tC*atan| <= 0.1*pi/2)
__device__ __forceinline__ float sin_small(float x) {
    float x2 = x * x;
    return x * (1.0f + x2 * (-1.66666667e-1f + x2 * 8.33333338e-3f));
}
// branchless full-range atan, max err ~1.5e-6 rad
__device__ __forceinline__ float fatanf(float x) {
    float ax = fabsf(x);
    bool big = ax > 1.0f;
    float z  = big ? __builtin_amdgcn_rcpf(ax) : ax;
    float z2 = z * z;
    float p = fmaf(z2, -0.0117212f, 0.05265332f);
    p = fmaf(z2, p, -0.11643287f);
    p = fmaf(z2, p,  0.19354346f);
    p = fmaf(z2, p, -0.33262347f);
    p = fmaf(z2, p,  0.99997726f);
    float r = z * p;
    r = big ? (1.57079632679489662f - r) : r;
    return copysignf(r, x);
}

// W1 element in the padded k-domain: k = cat*6 + t (t=0..4 data, t=5 pad).
__device__ __forceinline__ float w1_elem(const float* w1, int o, int k) {
    int cat = k / 6;
    int t = k - 6 * cat;
    return (t < 5 && k < 30) ? w1[o * 25 + cat * 5 + t] : 0.0f;
}

__global__ __launch_bounds__(256)
void sim_kernel(const float* __restrict__ fs,   // (B,5,8)
                const float* __restrict__ act,  // (B,50,2)
                const float* __restrict__ w1,   // (16,25) [o][k]
                const float* __restrict__ b1,   // (16)
                const float* __restrict__ w2,   // (3,16)
                const float* __restrict__ b2,   // (3)
                const float* __restrict__ prm,  // (10)
                const int*   __restrict__ rnnp, // (1)
                float* __restrict__ out)        // (B,50,8)
{
    // 4 waves x 64 rows x 32 uints (128B rows, only uints 0..15 used; the
    // slack enables the (row&7)<<4 XOR swizzle for conflict-free b128/b64).
    __shared__ unsigned int sF[8192];

    const int tid  = threadIdx.x;
    const int lane = tid & 63;
    const int wid  = tid >> 6;
    const int gg   = lane >> 4;   // k-block group (0..3)
    const int mm   = lane & 15;   // row/col within 16-tile
    unsigned int* wbase = &sF[wid * 2048];

    const int swz = (lane & 7) << 2;  // XOR swizzle in uint units (16B blocks)

    // write pointers: my row = lane (uints 0..15, 4x b128)
    unsigned int* wp0 = &wbase[lane * 32 + (0  ^ swz)];
    unsigned int* wp1 = &wbase[lane * 32 + (4  ^ swz)];
    unsigned int* wp2 = &wbase[lane * 32 + (8  ^ swz)];
    unsigned int* wp3 = &wbase[lane * 32 + (12 ^ swz)];
    // read pointers: frag q reads row 16q+mm ((16q+mm)&7 == lane&7 -> same swz)
#define DECL_RP(Q, H) \
    const uint2* rp##Q##H = (const uint2*)&wbase[(16 * (Q) + mm) * 32 + \
                                                 ((2 * gg + 8 * (H)) ^ swz)];
    DECL_RP(0,0) DECL_RP(0,1) DECL_RP(1,0) DECL_RP(1,1)
    DECL_RP(2,0) DECL_RP(2,1) DECL_RP(3,0) DECL_RP(3,1)
#undef DECL_RP

    const int car = blockIdx.x * 256 + tid;

    const float4* fsp = reinterpret_cast<const float4*>(fs + (size_t)car * 40);
    const float4* ap  = reinterpret_cast<const float4*>(act + (size_t)car * 100);
    float4 acur = ap[0];

    float wf[40];
#pragma unroll
    for (int i = 0; i < 10; ++i) {
        float4 v = fsp[i];
        wf[i * 4 + 0] = v.x; wf[i * 4 + 1] = v.y;
        wf[i * 4 + 2] = v.z; wf[i * 4 + 3] = v.w;
    }

    // wave-uniform physics params -> SGPR
    const float lf = rfl(prm[0]), lr = rfl(prm[1]), mIz = rfl(prm[2]);
    const float cm1 = rfl(prm[3]), cm2 = rfl(prm[4]), cr = rfl(prm[5]);
    const float cd = rfl(prm[6]);
    const float tB = rfl(prm[7]), tC = rfl(prm[8]), tD = rfl(prm[9]);
    const int   rnn = __builtin_amdgcn_readfirstlane(rnnp[0]);
    const float dt = 0.01f;
    const float PI = 3.14159265358979323846f;
    const float INV2PI = 0.15915494309189535f;
    const float TWOPI = 6.28318530717958647692f;

    // ---- A-fragments (prologue-only global loads, tiny) ----
    // fc1 W1: row o=mm, k-halves kb=4gg and 16+4gg, split hi/lo f16.
    h4_t a1h0, a1l0, a1h1, a1l1;
    {
        unsigned int h[8], l[8];
#pragma unroll
        for (int j = 0; j < 4; ++j) split16(w1_elem(w1, mm, 4 * gg + j), h[j], l[j]);
#pragma unroll
        for (int j = 0; j < 4; ++j) split16(w1_elem(w1, mm, 16 + 4 * gg + j), h[4 + j], l[4 + j]);
        a1h0 = mk_h4(h[0] | (h[1] << 16), h[2] | (h[3] << 16));
        a1l0 = mk_h4(l[0] | (l[1] << 16), l[2] | (l[3] << 16));
        a1h1 = mk_h4(h[4] | (h[5] << 16), h[6] | (h[7] << 16));
        a1l1 = mk_h4(l[4] | (l[5] << 16), l[6] | (l[7] << 16));
    }
    // fc2 W2: rows 0..2 valid (rows 3..15 zero), k = o1 = 4gg+j.
    h4_t a2h, a2l;
    {
        unsigned int h[4], l[4];
#pragma unroll
        for (int j = 0; j < 4; ++j) {
            float v = (mm < 3) ? w2[mm * 16 + 4 * gg + j] : 0.0f;
            split16(v, h[j], l[j]);
        }
        a2h = mk_h4(h[0] | (h[1] << 16), h[2] | (h[3] << 16));
        a2l = mk_h4(l[0] | (l[1] << 16), l[2] | (l[3] << 16));
    }
    // C operands: c1 = b1 rows 4gg..4gg+3 ; c2 = b2 rows (g==0, r<3 only)
    f32x4 c1;
    {
        float4 v = *reinterpret_cast<const float4*>(b1 + 4 * gg);
        c1[0] = v.x; c1[1] = v.y; c1[2] = v.z; c1[3] = v.w;
    }
    f32x4 c2;
    {
        float bz0 = b2[0], bz1 = b2[1], bz2 = b2[2];
        bool v = (lane < 16);
        c2[0] = v ? bz0 : 0.0f;
        c2[1] = v ? bz1 : 0.0f;
        c2[2] = v ? bz2 : 0.0f;
        c2[3] = 0.0f;
    }

    // ---- initial feature window: 15 packed-f16 uints (cat*3 + i) ----
    float vxh[5], vyh[5];
#pragma unroll
    for (int t = 0; t < 5; ++t) {
        float ph = wf[t * 8 + 4];
        float ch = __cosf(ph), sh = __sinf(ph);
        vxh[t] =  wf[t * 8 + 1] * ch + wf[t * 8 + 3] * sh;
        vyh[t] = -wf[t * 8 + 1] * sh + wf[t * 8 + 3] * ch;
    }
    unsigned int wu0_0 = pk_f16(vxh[0], vxh[1]);
    unsigned int wu0_1 = pk_f16(vxh[2], vxh[3]);
    unsigned int wu0_2 = cvt16(vxh[4]);
    unsigned int wu1_0 = pk_f16(vyh[0], vyh[1]);
    unsigned int wu1_1 = pk_f16(vyh[2], vyh[3]);
    unsigned int wu1_2 = cvt16(vyh[4]);
    unsigned int wu2_0 = pk_f16(wf[5],  wf[13]);
    unsigned int wu2_1 = pk_f16(wf[21], wf[29]);
    unsigned int wu2_2 = cvt16(wf[37]);
    unsigned int wu3_0 = pk_f16(wf[6],  wf[14]);
    unsigned int wu3_1 = pk_f16(wf[22], wf[30]);
    unsigned int wu3_2 = cvt16(wf[38]);
    unsigned int wu4_0 = pk_f16(wf[7],  wf[15]);
    unsigned int wu4_1 = pk_f16(wf[23], wf[31]);
    unsigned int wu4_2 = cvt16(wf[39]);

    float x = wf[32], y = wf[34], psi = wf[36];
    float c = __cosf(psi), s = __sinf(psi);
    float Vxc = vxh[4], Vyc = vyh[4];
    float thr_c = wf[38], str_c = wf[39];

    float* outp = out + (size_t)car * 400;

#pragma unroll 1
    for (int f2 = 0; f2 < 25; ++f2) {
        float4 anext = ap[(f2 < 24) ? (f2 + 1) : 24];

#pragma unroll
        for (int sub = 0; sub < 2; ++sub) {
            const float a0 = sub ? acur.z : acur.x;
            const float a1 = sub ? acur.w : acur.y;

            // stage current window (row = my car) -- same-wave DS is in-order,
            // no barrier needed; reads below hit rows written by this wave's
            // lanes in this same instruction stream.
            if (rnn) {
                *reinterpret_cast<uint4*>(wp0) = make_uint4(wu0_0, wu0_1, wu0_2, wu1_0);
                *reinterpret_cast<uint4*>(wp1) = make_uint4(wu1_1, wu1_2, wu2_0, wu2_1);
                *reinterpret_cast<uint4*>(wp2) = make_uint4(wu2_2, wu3_0, wu3_1, wu3_2);
                *reinterpret_cast<uint4*>(wp3) = make_uint4(wu4_0, wu4_1, wu4_2, 0u);
            }

            // ---- physics (pre-RNN), f32, overlaps LDS latency ----
            const float atr    = fatanf(Vyc * __builtin_amdgcn_rcpf(Vxc));
            const float slip_f = -atr + str_c;
            const float slip_r = -atr;
            const float laf = tD * sin_small(tC * fatanf(tB * slip_f));
            const float lar = tD * sin_small(tC * fatanf(tB * slip_r));
            const float st_s = __sinf(str_c), st_c = __cosf(str_c);
            const float fwd  = (cm1 - cm2 * Vxc) * thr_c - cr - cd * Vxc * Vxc;

            float Vx2   = Vxc + (fwd - laf * st_s) * dt;
            float Vy2   = Vyc + (lar + laf * st_c) * dt;
            float omega = mIz * (laf * lf * st_c - lar * lr) * dt;

            if (rnn) {
                // ---- B-fragment reads (8x ds_read_b64) ----
                uint2 b00 = *rp00, b01 = *rp01, b10 = *rp10, b11 = *rp11;
                uint2 b20 = *rp20, b21 = *rp21, b30 = *rp30, b31 = *rp31;

                // ---- fc1: 16 MFMAs ----
                f32x4 d0 = c1, d1 = c1, d2 = c1, d3 = c1;
#define FC1(D, BL, BH)                                   \
                D = mfma16(a1l0, mk_h4(BL.x, BL.y), D);  \
                D = mfma16(a1h0, mk_h4(BL.x, BL.y), D);  \
                D = mfma16(a1l1, mk_h4(BH.x, BH.y), D);  \
                D = mfma16(a1h1, mk_h4(BH.x, BH.y), D);
                FC1(d0, b00, b01) FC1(d1, b10, b11)
                FC1(d2, b20, b21) FC1(d3, b30, b31)
#undef FC1

                // ---- tanh + pack: D-frag -> B-frag of fc2 (same mapping) ----
                h4_t th0 = mk_h4(pk_f16(fast_tanhf(d0[0]), fast_tanhf(d0[1])),
                                 pk_f16(fast_tanhf(d0[2]), fast_tanhf(d0[3])));
                h4_t th1 = mk_h4(pk_f16(fast_tanhf(d1[0]), fast_tanhf(d1[1])),
                                 pk_f16(fast_tanhf(d1[2]), fast_tanhf(d1[3])));
                h4_t th2 = mk_h4(pk_f16(fast_tanhf(d2[0]), fast_tanhf(d2[1])),
                                 pk_f16(fast_tanhf(d2[2]), fast_tanhf(d2[3])));
                h4_t th3 = mk_h4(pk_f16(fast_tanhf(d3[0]), fast_tanhf(d3[1])),
                                 pk_f16(fast_tanhf(d3[2]), fast_tanhf(d3[3])));

                // ---- fc2: 8 MFMAs (z rows 0..2 live in lanes 0..15) ----
                f32x4 e0 = mfma16(a2h, th0, mfma16(a2l, th0, c2));
                f32x4 e1 = mfma16(a2h, th1, mfma16(a2l, th1, c2));
                f32x4 e2 = mfma16(a2h, th2, mfma16(a2l, th2, c2));
                f32x4 e3 = mfma16(a2h, th3, mfma16(a2l, th3, c2));

                // ---- broadcast z from lane mm, select own frag q=gg ----
                float q0z0 = __shfl(e0[0], mm, 64), q0z1 = __shfl(e0[1], mm, 64), q0z2 = __shfl(e0[2], mm, 64);
                float q1z0 = __shfl(e1[0], mm, 64), q1z1 = __shfl(e1[1], mm, 64), q1z2 = __shfl(e1[2], mm, 64);
                float q2z0 = __shfl(e2[0], mm, 64), q2z1 = __shfl(e2[1], mm, 64), q2z2 = __shfl(e2[2], mm, 64);
                float q3z0 = __shfl(e3[0], mm, 64), q3z1 = __shfl(e3[1], mm, 64), q3z2 = __shfl(e3[2], mm, 64);
                bool s1 = (lane & 16) != 0, s2 = (lane & 32) != 0;
                float z0 = s2 ? (s1 ? q3z0 : q2z0) : (s1 ? q1z0 : q0z0);
                float z1 = s2 ? (s1 ? q3z1 : q2z1) : (s1 ? q1z1 : q0z1);
                float z2 = s2 ? (s1 ? q3z2 : q2z2) : (s1 ? q1z2 : q0z2);

                Vx2   += fast_tanhf(z0) * 5.0f * dt;
                Vy2   += fast_tanhf(z1) * 5.0f * dt;
                omega += fast_tanhf(z2) * 3.0f * dt;
            }

            // ---- global-frame update ----
            const float Vxg = Vx2 * c - Vy2 * s;
            const float Vyg = Vx2 * s + Vy2 * c;
            float pn = psi + omega * dt + PI;
            pn = pn - floorf(pn * INV2PI) * TWOPI - PI;

            x = x + Vxg * dt;
            y = y + Vyg * dt;

            float4 o0 = make_float4(x, Vxg, y, Vyg);
            float4 o1 = make_float4(pn, omega, a0, a1);
            reinterpret_cast<float4*>(outp)[0] = o0;
            reinterpret_cast<float4*>(outp)[1] = o1;
            outp += 8;

            // ---- advance state, shift window (alignbit), insert new ----
            psi = pn;
            c = __cosf(pn);
            s = __sinf(pn);
            float nVx =  Vxg * c + Vyg * s;
            float nVy = -Vxg * s + Vyg * c;
#define SHIFTCAT(C, NEWV)                                              \
            wu##C##_0 = __builtin_amdgcn_alignbit(wu##C##_1, wu##C##_0, 16); \
            wu##C##_1 = __builtin_amdgcn_alignbit(wu##C##_2, wu##C##_1, 16); \
            wu##C##_2 = cvt16(NEWV);
            SHIFTCAT(0, nVx) SHIFTCAT(1, nVy) SHIFTCAT(2, omega)
            SHIFTCAT(3, a0)  SHIFTCAT(4, a1)
#undef SHIFTCAT
            Vxc = nVx; Vyc = nVy; thr_c = a0; str_c = a1;
        }
        acur = anext;
    }
}

extern "C" void kernel_launch(void* const* d_in, const int* in_sizes, int n_in,
                              void* d_out, int out_size, void* d_ws, size_t ws_size,
                              hipStream_t stream) {
    const float* fs  = (const float*)d_in[0];
    const float* act = (const float*)d_in[1];
    const float* w1  = (const float*)d_in[2];
    const float* b1  = (const float*)d_in[3];
    const float* w2  = (const float*)d_in[4];
    const float* b2  = (const float*)d_in[5];
    const float* prm = (const float*)d_in[6];
    const int*   rnn = (const int*)d_in[7];
    float* out = (float*)d_out;

    const int Bn = in_sizes[0] / 40;  // 65536 cars, 1 thread each
    dim3 grid(Bn / 256), block(256);
    hipLaunchKernelGGL(sim_kernel, grid, block, 0, stream,
                       fs, act, w1, b1, w2, b2, prm, rnn, out);
}